// Round 15
// baseline (97.171 us; speedup 1.0000x reference)
//
#include <hip/hip_runtime.h>
#include <hip/hip_bf16.h>
#include <math.h>

// R15: BARRIER-FREE self-paced waves.
// R11-R14: four packings/pipelines all land 24-27us; VALUBusy ~24% @ 47% occ
// -> waves idle in collective drain+barrier. This round: each WAVE owns a
// 1-row x 16-px tile, stages its own 3x18 halo (27 loads/lane) + depth into
// a wave-PRIVATE LDS region (4.3KB/wave). NO __syncthreads anywhere; wave
// ds_write->ds_read is in-order. Issue order xv -> depth -> wa lets compute
// start draining while wa still outstanding. 16K independent waves = pure
// uncoupled TLP.

#define ALPHA_F 8.3f

constexpr int B_    = 4;
constexpr int CIN   = 32;
constexpr int COUT  = 32;
constexpr int H_    = 256;
constexpr int W_    = 256;
constexpr int KTAPS = 9;
constexpr int HW    = H_ * W_;
constexpr int PXH   = 18;    // 16 px + 2 halo
constexpr int CP    = 40;    // padded channel stride (80 B: b128-aligned, bank-spread)

typedef __attribute__((ext_vector_type(8))) short bf16x8;
typedef __attribute__((ext_vector_type(4))) float f32x4;

static __device__ __forceinline__ short f2bf(float f) {
    __hip_bfloat16 h = __float2bfloat16(f);
    return __builtin_bit_cast(short, h);
}

// ---- prep: weights into per-lane A-fragment layout (verified R2-R14) ----
__global__ void prep_wfrag(const float* __restrict__ w, short* __restrict__ wf) {
    int idx = blockIdx.x * 256 + threadIdx.x;
    if (idx >= KTAPS * 2 * 64 * 8) return;
    int e  = idx & 7;
    int l  = (idx >> 3) & 63;
    int t  = (idx >> 9) & 1;
    int ij = idx >> 10;
    int o  = t * 16 + (l & 15);
    int c  = (l >> 4) * 8 + e;
    wf[idx] = f2bf(w[(o * CIN + c) * KTAPS + ij]);
}

// ---- fused main kernel: 1 wave = 1 row x 16 px, no barriers ----
__global__ __launch_bounds__(256, 4)
void dconv_wave(const float* __restrict__ x,
                const float* __restrict__ depth,
                const short* __restrict__ wf,
                float* __restrict__ out) {
    __shared__ __align__(16) short xsw[4][3][PXH][CP];  // 17,280 B (wave-private regions)
    __shared__ float dshw[4][3][PXH];                   //    864 B

    // XCD-bijective swizzle: 4096 blocks, 4096 % 8 == 0
    const int bid  = (int)blockIdx.x;
    const int bswz = (bid & 7) * 512 + (bid >> 3);

    const int tid  = threadIdx.x;
    const int wix  = tid >> 6;            // wave within block
    const int lane = tid & 63;
    const int wid  = bswz * 4 + wix;      // global wave id, [0, 16384)

    const int b   = wid >> 12;            // image
    const int h   = (wid >> 4) & 255;     // output row
    const int px0 = (wid & 15) << 4;      // 16-px segment base

    const float* xb  = x + (size_t)b * CIN * HW;
    const float* dpl = depth + (size_t)b * HW;

    // ---- ISSUE: 27 x-loads (3 rows x 32 ch x 18 px = 1728 = 27/lane) ----
    float xv[27];
#pragma unroll
    for (int i = 0; i < 27; ++i) {
        const int u  = i * 64 + lane;
        const int q  = u % PXH;           // px in halo  (magic-div, const)
        const int rc = u / PXH;
        const int c  = rc & 31;
        const int r  = rc >> 5;           // 0..2
        const int row = h + r - 1;
        const int wx  = px0 + q - 1;
        const int rowc = ((unsigned)row < (unsigned)H_) ? row : h;
        const int wxc  = ((unsigned)wx  < (unsigned)W_) ? wx  : px0;
        xv[i] = xb[(size_t)c * HW + rowc * W_ + wxc];
    }
    // ---- ISSUE: depth (54 values, lanes 0..53) ----
    float dv;
    {
        const int q   = lane % PXH;
        const int r   = lane / PXH;       // <3 for lane<54
        const int row = h + (r % 3) - 1;
        const int wx  = px0 + q - 1;
        const bool ok = (lane < 54) &&
                        ((unsigned)row < (unsigned)H_) &&
                        ((unsigned)wx  < (unsigned)W_);
        dv = dpl[ok ? (row * W_ + wx) : 0];
    }
    // ---- ISSUE: wa fragments last (18 x b128; drain under compute) ----
    const bf16x8* wfv = (const bf16x8*)wf;
    bf16x8 wa[2 * KTAPS];
#pragma unroll
    for (int k = 0; k < 2 * KTAPS; ++k) wa[k] = wfv[k * 64 + lane];

    // ---- WRITE: convert + wave-private LDS (no barrier needed) ----
#pragma unroll
    for (int i = 0; i < 27; ++i) {
        const int u  = i * 64 + lane;
        const int q  = u % PXH;
        const int rc = u / PXH;
        const int c  = rc & 31;
        const int r  = rc >> 5;
        const bool ok = ((unsigned)(h + r - 1) < (unsigned)H_) &&
                        ((unsigned)(px0 + q - 1) < (unsigned)W_);
        xsw[wix][r][q][c] = f2bf(ok ? xv[i] : 0.f);
    }
    if (lane < 54) {
        const int q = lane % PXH;
        const int r = lane / PXH;
        const bool ok = ((unsigned)(h + r - 1) < (unsigned)H_) &&
                        ((unsigned)(px0 + q - 1) < (unsigned)W_);
        dshw[wix][r][q] = ok ? dv : 0.f;
    }

    // ---- compute: one 16-px subtile ----
    const int n  = lane & 15;             // pixel (B/C-frag col)
    const int cg = (lane >> 4) * 8;       // channel group
    const int wp = px0 + n;

    const float dc = dshw[wix][1][n + 1];

    float s[KTAPS];
#pragma unroll
    for (int ij = 0; ij < KTAPS; ++ij) {
        const int di = ij / 3 - 1;
        const int dj = ij % 3 - 1;
        const bool ok = ((unsigned)(h + di) < (unsigned)H_) &&
                        ((unsigned)(wp + dj) < (unsigned)W_);
        s[ij] = ok ? __expf(-ALPHA_F * fabsf(dc - dshw[wix][1 + di][n + 1 + dj])) : 0.f;
    }

    f32x4 acc0 = {0.f, 0.f, 0.f, 0.f};
    f32x4 acc1 = {0.f, 0.f, 0.f, 0.f};
    const f32x4 z = {0.f, 0.f, 0.f, 0.f};
#pragma unroll
    for (int ij = 0; ij < KTAPS; ++ij) {
        const int di = ij / 3 - 1;
        const int dj = ij % 3 - 1;
        const bf16x8 bfrag = *(const bf16x8*)&xsw[wix][1 + di][n + 1 + dj][cg];
        const f32x4 t0 = __builtin_amdgcn_mfma_f32_16x16x32_bf16(wa[ij * 2 + 0], bfrag, z, 0, 0, 0);
        const f32x4 t1 = __builtin_amdgcn_mfma_f32_16x16x32_bf16(wa[ij * 2 + 1], bfrag, z, 0, 0, 0);
#pragma unroll
        for (int j = 0; j < 4; ++j) {
            acc0[j] = fmaf(s[ij], t0[j], acc0[j]);
            acc1[j] = fmaf(s[ij], t1[j], acc1[j]);
        }
    }

    // ---- epilogue: strided nontemporal stores (proven fast, R7 abl) ----
    const int orow = (lane >> 4) * 4;
    float* ob = out + (size_t)b * COUT * HW + h * W_ + wp;
#pragma unroll
    for (int j = 0; j < 4; ++j) {
        __builtin_nontemporal_store(acc0[j], ob + (size_t)(orow + j) * HW);
        __builtin_nontemporal_store(acc1[j], ob + (size_t)(orow + j + 16) * HW);
    }
}

// ---------- fp32 fallback (R1 kernel) ----------
__global__ __launch_bounds__(256)
void dconv_fallback(const float* __restrict__ x,
                    const float* __restrict__ depth,
                    const float* __restrict__ wgt,
                    float* __restrict__ out) {
    const int w  = threadIdx.x;
    const int bh = blockIdx.x;
    const int b  = bh >> 8;
    const int h  = bh & 255;

    const float* dplane = depth + (size_t)b * HW;
    const float  dc     = dplane[h * W_ + w];

    float acc[COUT];
#pragma unroll
    for (int o = 0; o < COUT; ++o) acc[o] = 0.f;

    const float* xb = x + (size_t)b * CIN * HW;

    for (int i = 0; i < 3; ++i) {
        const int  hh  = h + i - 1;
        const bool okh = ((unsigned)hh < (unsigned)H_);
        for (int j = 0; j < 3; ++j) {
            const int  ww = w + j - 1;
            const bool ok = okh && ((unsigned)ww < (unsigned)W_);
            const int  ij = i * 3 + j;
            const float dpv = ok ? dplane[hh * W_ + ww] : 0.f;
            const float sv  = __expf(-ALPHA_F * fabsf(dc - dpv));
            const int base = hh * W_ + ww;
#pragma unroll
            for (int c = 0; c < CIN; ++c) {
                const float v = (ok ? xb[c * HW + base] : 0.f) * sv;
#pragma unroll
                for (int o = 0; o < COUT; ++o) {
                    acc[o] = fmaf(v, wgt[(o * CIN + c) * KTAPS + ij], acc[o]);
                }
            }
        }
    }

    float* ob = out + ((size_t)b * COUT * H_ + h) * W_ + w;
#pragma unroll
    for (int o = 0; o < COUT; ++o) ob[o * HW] = acc[o];
}

extern "C" void kernel_launch(void* const* d_in, const int* in_sizes, int n_in,
                              void* d_out, int out_size, void* d_ws, size_t ws_size,
                              hipStream_t stream) {
    const float* x     = (const float*)d_in[0];
    const float* depth = (const float*)d_in[1];
    const float* wgt   = (const float*)d_in[2];
    float*       out   = (float*)d_out;

    const size_t wf_bytes = (size_t)(KTAPS * 2 * 64 * 8) * sizeof(short); // 18 KB

    if (ws_size >= wf_bytes) {
        short* wf = (short*)d_ws;
        prep_wfrag<<<(KTAPS * 2 * 64 * 8 + 255) / 256, 256, 0, stream>>>(wgt, wf);
        dconv_wave<<<4096, 256, 0, stream>>>(x, depth, wf, out);
    } else {
        dconv_fallback<<<B_ * H_, 256, 0, stream>>>(x, depth, wgt, out);
    }
}

// Round 16
// 53.974 us; speedup vs baseline: 1.8003x; 1.8003x over previous
//
#include <hip/hip_runtime.h>
#include <hip/hip_bf16.h>
#include <math.h>

// R16: two-kernel direct-load formulation, done right this time.
//   prep_xt: NCHW fp32 -> NHWC bf16 (pure streaming, fill-rate ~8us; xt then
//            L2/L3-warm for main).
//   dconv_direct: NO LDS, NO barriers. Per wave: 16-px tile; 9 tap B-frags
//            loaded directly as dwordx4 (each tap = 1KB line-exact per wave),
//            wa[18] hoisted, everything batched (R8 discipline),
//            launch_bounds(256,3) -> 170 VGPR cap so the ~145-reg batch is
//            NOT sunk (R9/R10/R15 lesson: compiler serializes when capped).
//            16K independent waves = 5.3 generations = continuous stream.
// R3/R4 ran this shape with VGPR=32 serialized codegen + per-tap wf loads;
// this is the fair test.

#define ALPHA_F 8.3f

constexpr int B_    = 4;
constexpr int CIN   = 32;
constexpr int COUT  = 32;
constexpr int H_    = 256;
constexpr int W_    = 256;
constexpr int KTAPS = 9;
constexpr int HW    = H_ * W_;

typedef __attribute__((ext_vector_type(8))) short bf16x8;
typedef __attribute__((ext_vector_type(4))) float f32x4;

static __device__ __forceinline__ short f2bf(float f) {
    __hip_bfloat16 h = __float2bfloat16(f);
    return __builtin_bit_cast(short, h);
}

// ---- prep 1: weights into per-lane A-fragment layout (verified R2-R15) ----
__global__ void prep_wfrag(const float* __restrict__ w, short* __restrict__ wf) {
    int idx = blockIdx.x * 256 + threadIdx.x;
    if (idx >= KTAPS * 2 * 64 * 8) return;
    int e  = idx & 7;
    int l  = (idx >> 3) & 63;
    int t  = (idx >> 9) & 1;
    int ij = idx >> 10;
    int o  = t * 16 + (l & 15);
    int c  = (l >> 4) * 8 + e;
    wf[idx] = f2bf(w[(o * CIN + c) * KTAPS + ij]);
}

// ---- prep 2: x NCHW fp32 -> NHWC bf16, float4-wide (verified R4 passes) ----
__global__ __launch_bounds__(256)
void prep_xt(const float* __restrict__ x, short* __restrict__ xt) {
    const int tid = blockIdx.x * 256 + threadIdx.x;   // 65536 threads
    const int p4  = tid << 2;
    const int b   = p4 >> 16;
    const int pix = p4 & (HW - 1);
    const float* xb  = x + (size_t)b * CIN * HW + pix;
    short*       dst = xt + (size_t)(b * HW + pix) * CIN;

#pragma unroll
    for (int g = 0; g < 4; ++g) {                     // channel groups of 8
        f32x4 v[8];
#pragma unroll
        for (int e = 0; e < 8; ++e) {
            v[e] = *(const f32x4*)(xb + (size_t)(g * 8 + e) * HW);
        }
#pragma unroll
        for (int q = 0; q < 4; ++q) {                 // pixel within float4
            bf16x8 o;
#pragma unroll
            for (int e = 0; e < 8; ++e) o[e] = f2bf(v[e][q]);
            *(bf16x8*)(dst + q * CIN + g * 8) = o;
        }
    }
}

// ---- main: no LDS, no barriers, fully batched per-wave direct loads ----
__global__ __launch_bounds__(256, 3)
void dconv_direct(const short* __restrict__ xt,
                  const float* __restrict__ depth,
                  const short* __restrict__ wf,
                  float* __restrict__ out) {
    // XCD-bijective swizzle: 4096 blocks, 4096 % 8 == 0
    const int bid  = (int)blockIdx.x;
    const int bswz = (bid & 7) * 512 + (bid >> 3);

    const int tid  = threadIdx.x;
    const int lane = tid & 63;
    const int wid  = bswz * 4 + (tid >> 6);   // [0, 16384); block = 64 px run

    const int b   = wid >> 12;                // image
    const int h   = (wid >> 4) & 255;         // output row
    const int px0 = (wid & 15) << 4;          // 16-px segment
    const int n   = lane & 15;                // B/C-frag col (pixel)
    const int cg  = (lane >> 4) * 8;          // channel group
    const int wp  = px0 + n;
    const int pix = h * W_ + wp;

    const short* xtb = xt + (size_t)b * HW * CIN;
    const float* dpl = depth + (size_t)b * HW;

    // ---- offsets (VALU only) ----
    int  off[KTAPS];
    bool okk[KTAPS];
#pragma unroll
    for (int ij = 0; ij < KTAPS; ++ij) {
        const int di = ij / 3 - 1;
        const int dj = ij % 3 - 1;
        const bool ok = ((unsigned)(h + di) < (unsigned)H_) &&
                        ((unsigned)(wp + dj) < (unsigned)W_);
        okk[ij] = ok;
        off[ij] = ok ? (di * W_ + dj) : 0;    // clamped addr when !ok
    }

    // ---- ISSUE oldest-first: depth (drained first, into sims) ----
    const float dc = dpl[pix];
    float dp[KTAPS];
#pragma unroll
    for (int ij = 0; ij < KTAPS; ++ij) dp[ij] = dpl[pix + off[ij]];

    // ---- ISSUE: 9 tap B-frags (dwordx4 each; wave covers 1KB line-exact) --
    bf16x8 bfv[KTAPS];
#pragma unroll
    for (int ij = 0; ij < KTAPS; ++ij) {
        bfv[ij] = *(const bf16x8*)(xtb + (size_t)(pix + off[ij]) * CIN + cg);
    }

    // ---- ISSUE newest: wa fragments (drain under sims/first MFMAs) ----
    const bf16x8* wfv = (const bf16x8*)wf;
    bf16x8 wa[2 * KTAPS];
#pragma unroll
    for (int k = 0; k < 2 * KTAPS; ++k) wa[k] = wfv[k * 64 + lane];

    // ---- sims (waits only on depth: oldest loads) ----
    float s[KTAPS];
#pragma unroll
    for (int ij = 0; ij < KTAPS; ++ij) {
        s[ij] = okk[ij] ? __expf(-ALPHA_F * fabsf(dc - dp[ij])) : 0.f;
    }

    // ---- MFMA taps + post-scale ----
    f32x4 acc0 = {0.f, 0.f, 0.f, 0.f};
    f32x4 acc1 = {0.f, 0.f, 0.f, 0.f};
    const f32x4 z = {0.f, 0.f, 0.f, 0.f};
#pragma unroll
    for (int ij = 0; ij < KTAPS; ++ij) {
        const f32x4 t0 = __builtin_amdgcn_mfma_f32_16x16x32_bf16(wa[ij * 2 + 0], bfv[ij], z, 0, 0, 0);
        const f32x4 t1 = __builtin_amdgcn_mfma_f32_16x16x32_bf16(wa[ij * 2 + 1], bfv[ij], z, 0, 0, 0);
#pragma unroll
        for (int j = 0; j < 4; ++j) {
            acc0[j] = fmaf(s[ij], t0[j], acc0[j]);
            acc1[j] = fmaf(s[ij], t1[j], acc1[j]);
        }
    }

    // ---- epilogue: strided nontemporal stores (proven fast, R7 abl) ----
    const int orow = (lane >> 4) * 4;
    float* ob = out + (size_t)b * COUT * HW + pix;
#pragma unroll
    for (int j = 0; j < 4; ++j) {
        __builtin_nontemporal_store(acc0[j], ob + (size_t)(orow + j) * HW);
        __builtin_nontemporal_store(acc1[j], ob + (size_t)(orow + j + 16) * HW);
    }
}

// ---------- fp32 fallback (R1 kernel) ----------
__global__ __launch_bounds__(256)
void dconv_fallback(const float* __restrict__ x,
                    const float* __restrict__ depth,
                    const float* __restrict__ wgt,
                    float* __restrict__ out) {
    const int w  = threadIdx.x;
    const int bh = blockIdx.x;
    const int b  = bh >> 8;
    const int h  = bh & 255;

    const float* dplane = depth + (size_t)b * HW;
    const float  dc     = dplane[h * W_ + w];

    float acc[COUT];
#pragma unroll
    for (int o = 0; o < COUT; ++o) acc[o] = 0.f;

    const float* xb = x + (size_t)b * CIN * HW;

    for (int i = 0; i < 3; ++i) {
        const int  hh  = h + i - 1;
        const bool okh = ((unsigned)hh < (unsigned)H_);
        for (int j = 0; j < 3; ++j) {
            const int  ww = w + j - 1;
            const bool ok = okh && ((unsigned)ww < (unsigned)W_);
            const int  ij = i * 3 + j;
            const float dpv = ok ? dplane[hh * W_ + ww] : 0.f;
            const float sv  = __expf(-ALPHA_F * fabsf(dc - dpv));
            const int base = hh * W_ + ww;
#pragma unroll
            for (int c = 0; c < CIN; ++c) {
                const float v = (ok ? xb[c * HW + base] : 0.f) * sv;
#pragma unroll
                for (int o = 0; o < COUT; ++o) {
                    acc[o] = fmaf(v, wgt[(o * CIN + c) * KTAPS + ij], acc[o]);
                }
            }
        }
    }

    float* ob = out + ((size_t)b * COUT * H_ + h) * W_ + w;
#pragma unroll
    for (int o = 0; o < COUT; ++o) ob[o * HW] = acc[o];
}

extern "C" void kernel_launch(void* const* d_in, const int* in_sizes, int n_in,
                              void* d_out, int out_size, void* d_ws, size_t ws_size,
                              hipStream_t stream) {
    const float* x     = (const float*)d_in[0];
    const float* depth = (const float*)d_in[1];
    const float* wgt   = (const float*)d_in[2];
    float*       out   = (float*)d_out;

    const size_t wf_pad   = 32768;                                 // wf: 18KB used
    const size_t xt_bytes = (size_t)B_ * HW * CIN * sizeof(short); // 16.8 MB

    if (ws_size >= wf_pad + xt_bytes) {
        short* wf = (short*)d_ws;
        short* xt = (short*)((char*)d_ws + wf_pad);
        prep_wfrag<<<(KTAPS * 2 * 64 * 8 + 255) / 256, 256, 0, stream>>>(wgt, wf);
        prep_xt<<<B_ * HW / 4 / 256, 256, 0, stream>>>(x, xt);
        dconv_direct<<<4096, 256, 0, stream>>>(xt, depth, wf, out);
    } else {
        dconv_fallback<<<B_ * H_, 256, 0, stream>>>(x, depth, wgt, out);
    }
}

// Round 17
// 25.681 us; speedup vs baseline: 3.7838x; 2.1017x over previous
//
#include <hip/hip_runtime.h>
#include <hip/hip_bf16.h>
#include <math.h>

// R17: rolling-window STREAMING kernel.
// All ~24us kernels (R8-R14) share one big stage->drain->compute timeline;
// single-generation packing phase-aligns the whole machine (memory idle
// during compute, compute idle during drain). Fix: block = 64px x 8 rows,
// 8 unrolled iterations {issue row t+3 loads -> compute row t from 4-slot
// LDS ring -> drain+write -> barrier -> stores}. Ring slots mod 4 never
// collide (write slot t+3 vs read t..t+2) -> 1 barrier/iter. Each x row
// staged once (1.25x re-read). 512 blocks = 2/CU, (256,2) -> no reg sink.

#define ALPHA_F 8.3f

constexpr int B_    = 4;
constexpr int CIN   = 32;
constexpr int COUT  = 32;
constexpr int H_    = 256;
constexpr int W_    = 256;
constexpr int KTAPS = 9;
constexpr int HW    = H_ * W_;
constexpr int SROWS = 8;

typedef __attribute__((ext_vector_type(8))) short bf16x8;
typedef __attribute__((ext_vector_type(4))) float f32x4;

static __device__ __forceinline__ short f2bf(float f) {
    __hip_bfloat16 h = __float2bfloat16(f);
    return __builtin_bit_cast(short, h);
}
static __device__ __forceinline__ int packbf(float f0, float f1) {
    return (int)(unsigned short)f2bf(f0) | ((int)(unsigned short)f2bf(f1) << 16);
}

// ---- prep: weights into per-lane A-fragment layout (verified R2-R16) ----
__global__ void prep_wfrag(const float* __restrict__ w, short* __restrict__ wf) {
    int idx = blockIdx.x * 256 + threadIdx.x;
    if (idx >= KTAPS * 2 * 64 * 8) return;
    int e  = idx & 7;
    int l  = (idx >> 3) & 63;
    int t  = (idx >> 9) & 1;
    int ij = idx >> 10;
    int o  = t * 16 + (l & 15);
    int c  = (l >> 4) * 8 + e;
    wf[idx] = f2bf(w[(o * CIN + c) * KTAPS + ij]);
}

// ---- streaming main kernel ----
__global__ __launch_bounds__(256, 2)
void dconv_stream(const float* __restrict__ x,
                  const float* __restrict__ depth,
                  const short* __restrict__ wf,
                  float* __restrict__ out) {
    __shared__ __align__(16) short xs[4][66][40];   // 4-slot ring, 21,120 B
    __shared__ float dsr[4][66];                    //  1,056 B

    // XCD-bijective swizzle: 512 blocks, 512 % 8 == 0
    const int bid   = (int)blockIdx.x;
    const int bswz  = (bid & 7) * 64 + (bid >> 3);
    const int b     = bswz >> 7;          // image
    const int strip = (bswz >> 2) & 31;   // 32 strips of 8 rows
    const int wseg  = (bswz & 3) << 6;    // 64-px column segment
    const int h0    = strip << 3;
    const int tid   = threadIdx.x;
    const int lane  = tid & 63;
    const float* xb  = x + (size_t)b * CIN * HW;
    const float* dpl = depth + (size_t)b * HW;

    // ======= PROLOGUE: stage rows lr=0,1,2 (global h0-1..h0+1) =======
    float pv0[12], pv1[12];
#pragma unroll
    for (int u = 0; u < 12; ++u) {
        const int idx = u * 256 + tid;
        const int q   = idx & 63;
        const int cp  = (idx >> 6) & 15;
        const int lr  = idx >> 10;                    // 0..2
        const int rg  = h0 - 1 + lr;
        const int rc  = ((unsigned)rg < (unsigned)H_) ? rg : h0;
        const size_t gb = (size_t)(2 * cp) * HW + rc * W_ + wseg + q;
        pv0[u] = xb[gb];
        pv1[u] = xb[gb + HW];
    }
    float ph0, ph1;
    {
        const int side = tid & 1;
        const int rc2  = tid >> 1;
        const int cp   = rc2 & 15;
        const int lr   = (rc2 >> 4) % 3;
        const int rg   = h0 - 1 + lr;
        const int wx   = wseg - 1 + side * 65;
        const bool ok  = (tid < 96) && ((unsigned)rg < (unsigned)H_) &&
                         ((unsigned)wx < (unsigned)W_);
        const size_t gb = (size_t)(2 * cp) * HW + (ok ? (size_t)(rg * W_ + wx) : 0);
        ph0 = xb[gb];
        ph1 = xb[gb + HW];
    }
    float pd;
    {
        const int lr = (tid < 198) ? (tid / 66) : 0;
        const int q  = (tid < 198) ? (tid - lr * 66) : 0;
        const int rg = h0 - 1 + lr;
        const int wx = wseg - 1 + q;
        const bool ok = ((unsigned)rg < (unsigned)H_) && ((unsigned)wx < (unsigned)W_);
        pd = dpl[ok ? (rg * W_ + wx) : 0];
    }
    // wa hoist: 18 fragments, drains with prologue loads
    const bf16x8* wfv = (const bf16x8*)wf;
    bf16x8 wa[2 * KTAPS];
#pragma unroll
    for (int k = 0; k < 2 * KTAPS; ++k) wa[k] = wfv[k * 64 + lane];

    // prologue writes
#pragma unroll
    for (int u = 0; u < 12; ++u) {
        const int idx = u * 256 + tid;
        const int q   = idx & 63;
        const int cp  = (idx >> 6) & 15;
        const int lr  = idx >> 10;
        const bool ok = ((unsigned)(h0 - 1 + lr) < (unsigned)H_);
        ((int*)&xs[lr][q + 1][0])[cp] = packbf(ok ? pv0[u] : 0.f, ok ? pv1[u] : 0.f);
    }
    if (tid < 96) {
        const int side = tid & 1;
        const int rc2  = tid >> 1;
        const int cp   = rc2 & 15;
        const int lr   = rc2 >> 4;                    // 0..2
        const int rg   = h0 - 1 + lr;
        const int wx   = wseg - 1 + side * 65;
        const bool ok  = ((unsigned)rg < (unsigned)H_) && ((unsigned)wx < (unsigned)W_);
        ((int*)&xs[lr][side * 65][0])[cp] = packbf(ok ? ph0 : 0.f, ok ? ph1 : 0.f);
    }
    if (tid < 198) {
        const int lr = tid / 66;
        const int q  = tid - lr * 66;
        const bool ok = ((unsigned)(h0 - 1 + lr) < (unsigned)H_) &&
                        ((unsigned)(wseg - 1 + q) < (unsigned)W_);
        dsr[lr][q] = ok ? pd : 0.f;
    }
    __syncthreads();

    // ======= STEADY STATE: 8 rows, rolling ring =======
    const int w    = tid >> 6;            // wave -> 16-px subtile of the row
    const int n    = lane & 15;
    const int cg   = (lane >> 4) * 8;
    const int pl   = w * 16 + n + 1;      // px_local in [1,64]
    const int wp   = wseg + w * 16 + n;
    const int orow = (lane >> 4) * 4;
    const f32x4 z  = {0.f, 0.f, 0.f, 0.f};

#pragma unroll
    for (int t = 0; t < SROWS; ++t) {
        // ---- 1) issue next-row loads (lr = t+3, global rg = h0+t+2) ----
        float sv0[4], sv1[4], sh0 = 0.f, sh1 = 0.f, sd = 0.f;
        const int  rg     = h0 + t + 2;
        const bool row_ok = ((unsigned)rg < (unsigned)H_);
        if (t < SROWS - 1) {
            const int rc = row_ok ? rg : h0;
#pragma unroll
            for (int u = 0; u < 4; ++u) {
                const int idx = u * 256 + tid;
                const int q   = idx & 63;
                const int cp  = idx >> 6;             // 0..15
                const size_t gb = (size_t)(2 * cp) * HW + rc * W_ + wseg + q;
                sv0[u] = xb[gb];
                sv1[u] = xb[gb + HW];
            }
            {
                const int side = tid & 1;
                const int cp   = (tid >> 1) & 15;
                const int wx   = wseg - 1 + side * 65;
                const bool ok  = (tid < 32) && row_ok && ((unsigned)wx < (unsigned)W_);
                const size_t gb = (size_t)(2 * cp) * HW + (ok ? (size_t)(rg * W_ + wx) : 0);
                sh0 = xb[gb];
                sh1 = xb[gb + HW];
            }
            {
                const int wx  = wseg - 1 + tid;
                const bool ok = (tid < 66) && row_ok && ((unsigned)wx < (unsigned)W_);
                sd = dpl[ok ? (rg * W_ + wx) : 0];
            }
        }

        // ---- 2) compute output row h = h0+t (ring slots t, t+1, t+2) ----
        const int h  = h0 + t;
        const int s0 = t & 3, s1 = (t + 1) & 3, s2 = (t + 2) & 3;
        const float dc = dsr[s1][pl];

        float s[KTAPS];
#pragma unroll
        for (int ij = 0; ij < KTAPS; ++ij) {
            const int di = ij / 3 - 1;
            const int dj = ij % 3 - 1;
            const int sl = (di < 0) ? s0 : ((di == 0) ? s1 : s2);
            const bool ok = ((unsigned)(h + di) < (unsigned)H_) &&
                            ((unsigned)(wp + dj) < (unsigned)W_);
            s[ij] = ok ? __expf(-ALPHA_F * fabsf(dc - dsr[sl][pl + dj])) : 0.f;
        }

        f32x4 acc0 = z, acc1 = z;
#pragma unroll
        for (int ij = 0; ij < KTAPS; ++ij) {
            const int di = ij / 3 - 1;
            const int dj = ij % 3 - 1;
            const int sl = (di < 0) ? s0 : ((di == 0) ? s1 : s2);
            const bf16x8 bfrag = *(const bf16x8*)&xs[sl][pl + dj][cg];
            const f32x4 t0 = __builtin_amdgcn_mfma_f32_16x16x32_bf16(wa[ij * 2 + 0], bfrag, z, 0, 0, 0);
            const f32x4 t1 = __builtin_amdgcn_mfma_f32_16x16x32_bf16(wa[ij * 2 + 1], bfrag, z, 0, 0, 0);
#pragma unroll
            for (int j = 0; j < 4; ++j) {
                acc0[j] = fmaf(s[ij], t0[j], acc0[j]);
                acc1[j] = fmaf(s[ij], t1[j], acc1[j]);
            }
        }

        // ---- 3) drain + write row lr=t+3 into ring slot (t+3)&3 ----
        // (slot t+3 mod 4 is disjoint from read slots t..t+2 -> race-free)
        if (t < SROWS - 1) {
            const int sw = (t + 3) & 3;
#pragma unroll
            for (int u = 0; u < 4; ++u) {
                const int idx = u * 256 + tid;
                const int q   = idx & 63;
                const int cp  = idx >> 6;
                ((int*)&xs[sw][q + 1][0])[cp] =
                    packbf(row_ok ? sv0[u] : 0.f, row_ok ? sv1[u] : 0.f);
            }
            if (tid < 32) {
                const int side = tid & 1;
                const int cp   = (tid >> 1) & 15;
                const int wx   = wseg - 1 + side * 65;
                const bool ok  = row_ok && ((unsigned)wx < (unsigned)W_);
                ((int*)&xs[sw][side * 65][0])[cp] =
                    packbf(ok ? sh0 : 0.f, ok ? sh1 : 0.f);
            }
            if (tid < 66) {
                const int wx  = wseg - 1 + tid;
                const bool ok = row_ok && ((unsigned)wx < (unsigned)W_);
                dsr[sw][tid] = ok ? sd : 0.f;
            }
        }
        __syncthreads();

        // ---- 4) stores (after barrier, fire-and-forget) ----
        float* ob = out + (size_t)b * COUT * HW + h * W_ + wp;
#pragma unroll
        for (int j = 0; j < 4; ++j) {
            __builtin_nontemporal_store(acc0[j], ob + (size_t)(orow + j) * HW);
            __builtin_nontemporal_store(acc1[j], ob + (size_t)(orow + j + 16) * HW);
        }
    }
}

// ---------- fp32 fallback (R1 kernel) ----------
__global__ __launch_bounds__(256)
void dconv_fallback(const float* __restrict__ x,
                    const float* __restrict__ depth,
                    const float* __restrict__ wgt,
                    float* __restrict__ out) {
    const int w  = threadIdx.x;
    const int bh = blockIdx.x;
    const int b  = bh >> 8;
    const int h  = bh & 255;

    const float* dplane = depth + (size_t)b * HW;
    const float  dc     = dplane[h * W_ + w];

    float acc[COUT];
#pragma unroll
    for (int o = 0; o < COUT; ++o) acc[o] = 0.f;

    const float* xb = x + (size_t)b * CIN * HW;

    for (int i = 0; i < 3; ++i) {
        const int  hh  = h + i - 1;
        const bool okh = ((unsigned)hh < (unsigned)H_);
        for (int j = 0; j < 3; ++j) {
            const int  ww = w + j - 1;
            const bool ok = okh && ((unsigned)ww < (unsigned)W_);
            const int  ij = i * 3 + j;
            const float dpv = ok ? dplane[hh * W_ + ww] : 0.f;
            const float sv  = __expf(-ALPHA_F * fabsf(dc - dpv));
            const int base = hh * W_ + ww;
#pragma unroll
            for (int c = 0; c < CIN; ++c) {
                const float v = (ok ? xb[c * HW + base] : 0.f) * sv;
#pragma unroll
                for (int o = 0; o < COUT; ++o) {
                    acc[o] = fmaf(v, wgt[(o * CIN + c) * KTAPS + ij], acc[o]);
                }
            }
        }
    }

    float* ob = out + ((size_t)b * COUT * H_ + h) * W_ + w;
#pragma unroll
    for (int o = 0; o < COUT; ++o) ob[o * HW] = acc[o];
}

extern "C" void kernel_launch(void* const* d_in, const int* in_sizes, int n_in,
                              void* d_out, int out_size, void* d_ws, size_t ws_size,
                              hipStream_t stream) {
    const float* x     = (const float*)d_in[0];
    const float* depth = (const float*)d_in[1];
    const float* wgt   = (const float*)d_in[2];
    float*       out   = (float*)d_out;

    const size_t wf_bytes = (size_t)(KTAPS * 2 * 64 * 8) * sizeof(short); // 18 KB

    if (ws_size >= wf_bytes) {
        short* wf = (short*)d_ws;
        prep_wfrag<<<(KTAPS * 2 * 64 * 8 + 255) / 256, 256, 0, stream>>>(wgt, wf);
        dconv_stream<<<512, 256, 0, stream>>>(x, depth, wf, out);
    } else {
        dconv_fallback<<<B_ * H_, 256, 0, stream>>>(x, depth, wgt, out);
    }
}